// Round 5
// baseline (1000.492 us; speedup 1.0000x reference)
//
#include <hip/hip_runtime.h>
#include <stdint.h>

// HMLSTM cell fused pipeline for MI355X (gfx950).
// Sizes fixed by the reference: B=8192, IBS=H=ITS=1024, K=3072, G=4096.
//
// Round 1: fused GEMM epilogue (gate-permuted B cols), ws 285->151 MB.
// Round 4: ws_size-ADAPTIVE M-chunking — A hi/lo chunk sized to fit the
// actual scratch; removes the unverifiable "ws >= 151 MB" assumption that
// round 0 may have violated. Single chunk (== audited round-1 behavior)
// whenever ws_size >= 151 MB.
//
// Workspace layout:
//   Bthi [4096][3072] u16 @ 0           (25,165,824 B)  rows = PERMUTED cols
//   Btlo [4096][3072] u16 @ 25165824    (25,165,824 B)
//   Ahi  [chunk][3072] u16 @ 50331648
//   Alo  [chunk][3072] u16 @ 50331648 + chunk*6144
//
// B-column permutation: source col n (gate = n>>10, unit = n&1023) is stored
// at row p = (unit>>5)*128 + gate*32 + (unit&31). Block bn then covers
// units bn*32..bn*32+31 x all 4 gates in one 128-wide tile.

typedef float f4 __attribute__((ext_vector_type(4)));
typedef float f32x4 __attribute__((ext_vector_type(4)));
typedef __bf16 bf16x8 __attribute__((ext_vector_type(8)));
typedef unsigned int u32;
typedef unsigned short u16;
typedef u16 u16x4 __attribute__((ext_vector_type(4)));

#define GLOBAL_AS __attribute__((address_space(1)))
#define LDS_AS __attribute__((address_space(3)))

__device__ __forceinline__ u16 bf16_rne(float x) {
  u32 u = __builtin_bit_cast(u32, x);
  u32 r = (u + 0x7fffu + ((u >> 16) & 1u)) >> 16;
  return (u16)r;
}
__device__ __forceinline__ float bf16_f32(u16 h) {
  u32 u = ((u32)h) << 16;
  return __builtin_bit_cast(float, u);
}
__device__ __forceinline__ float fast_sigmoid(float x) {
  return 1.0f / (1.0f + __expf(-x));
}
__device__ __forceinline__ float fast_tanh(float x) {
  return 2.0f / (1.0f + __expf(-2.0f * x)) - 1.0f;
}

// ---------------------------------------------------------------------------
// prep_a: A = [hb*zb | h | ht*z] -> bf16 hi/lo for batch rows
// [row0, row0+gridDim.x); A buffers indexed by LOCAL row (blockIdx.x).
// ---------------------------------------------------------------------------
__global__ __launch_bounds__(256) void prep_a(
    const float* __restrict__ hb, const float* __restrict__ h,
    const float* __restrict__ ht, const float* __restrict__ z,
    const float* __restrict__ zb, u16* __restrict__ Ahi, u16* __restrict__ Alo,
    int row0) {
  const int bl = blockIdx.x;           // local row in A chunk
  const int bg = row0 + bl;            // global batch row
  const int t = threadIdx.x;
  const float zf = z[bg], zbf = zb[bg];
  const float gates[3] = {zbf, 1.0f, zf};
  const float* srcs[3] = {hb, h, ht};
#pragma unroll
  for (int p = 0; p < 3; ++p) {
    const int col = p * 1024 + t * 4;
    f4 v = *(const f4*)(srcs[p] + (long)bg * 1024 + t * 4);
    const float gt = gates[p];
    u16x4 vhi, vlo;
#pragma unroll
    for (int q = 0; q < 4; ++q) {
      float x = v[q] * gt;
      u16 hi = bf16_rne(x);
      vhi[q] = hi;
      vlo[q] = bf16_rne(x - bf16_f32(hi));
    }
    *(u16x4*)(Ahi + (long)bl * 3072 + col) = vhi;
    *(u16x4*)(Alo + (long)bl * 3072 + col) = vlo;
  }
}

// ---------------------------------------------------------------------------
// prep_b: Bt[p][k] = cat(W,R,U)[k][n] with gate-permuted destination row p.
// 32x32 LDS-tiled transpose; grid=(128 n-tiles, 96 k-tiles), 256 threads.
// Source pitch is 4097 (sz column excluded here, handled by gemv).
// ---------------------------------------------------------------------------
__global__ __launch_bounds__(256) void prep_b(
    const float* __restrict__ W, const float* __restrict__ R,
    const float* __restrict__ U, u16* __restrict__ Bthi, u16* __restrict__ Btlo) {
  __shared__ float tile[32][33];
  const int tx = threadIdx.x & 31;
  const int ty = threadIdx.x >> 5;
  const int n0 = blockIdx.x * 32;
  const int k0 = blockIdx.y * 32;
  const int piece = k0 >> 10;       // k-tiles never straddle a 1024 boundary
  const int kp0 = k0 & 1023;
  const float* src = (piece == 0) ? W : ((piece == 1) ? R : U);
#pragma unroll
  for (int i = 0; i < 4; ++i) {
    const int kl = ty + i * 8;
    tile[kl][tx] = src[(long)(kp0 + kl) * 4097 + n0 + tx];
  }
  __syncthreads();
  const int gate = n0 >> 10;
  const int ubase = (((n0 & 1023) >> 5) << 7) + (gate << 5);  // p for nl=0
#pragma unroll
  for (int i = 0; i < 4; ++i) {
    const int nl = ty + i * 8;
    const float x = tile[tx][nl];
    const u16 hi = bf16_rne(x);
    const u16 lo = bf16_rne(x - bf16_f32(hi));
    const long p = ubase + nl;      // permuted destination row
    Bthi[p * 3072 + k0 + tx] = hi;
    Btlo[p * 3072 + k0 + tx] = lo;
  }
}

// ---------------------------------------------------------------------------
// gemm_fused: S = Ahi*Bhi + Ahi*Blo + Alo*Bhi (fp32 accum) with fused
// bias + activations + cell update epilogue, for batch rows
// [row0, row0 + (gridDim.x/32)*128).
// 128x128 tile, BK=32, 4 waves (each 64x64 = 4x4 frags of 16x16x32 MFMA).
// 4 LDS planes of [128][32] bf16 (32 KB), staged via global_load_lds w=16.
// XOR swizzle on 16B granules: LDS granule c of row r holds global granule
// c ^ ((r>>1)&3); swizzle applied on the GLOBAL source address (LDS dest
// stays linear — global_load_lds requirement), undone on the ds_read side.
// Epilogue reuses the 32 KB LDS as a fp32[64][128] tile, two row-halves.
// ---------------------------------------------------------------------------
__global__ __launch_bounds__(256, 2) void gemm_fused(
    const u16* __restrict__ Ahi, const u16* __restrict__ Alo,
    const u16* __restrict__ Bthi, const u16* __restrict__ Btlo,
    const float* __restrict__ bias, const float* __restrict__ c,
    const float* __restrict__ h, const float* __restrict__ z,
    const float* __restrict__ zb, float* __restrict__ out, int row0) {
  __shared__ u16 lds[16384];  // 4 planes x 4096 u16 = 32 KB
  const int t = threadIdx.x;
  const int w = t >> 6;
  const int l = t & 63;

  // XCD-bijective swizzle; gridDim.x = Mtiles*32 is always % 8 == 0.
  const int bid = blockIdx.x;
  const int cpx = gridDim.x >> 3;
  const int bid2 = (bid & 7) * cpx + (bid >> 3);
  const int bm = bid2 >> 5;   // M tile within chunk
  const int bn = bid2 & 31;   // unit-block: units bn*32..+31
  const long browl = (long)bm * 128;         // LOCAL A row base
  const long browg = row0 + browl;           // GLOBAL batch row base
  const long bcol = (long)bn * 128;          // permuted-B row base

  const u16* gp[4] = {Ahi, Alo, Bthi, Btlo};

  // Staging: 8 global_load_lds per thread per K-step. Instr j: plane j>>1,
  // half j&1. Linear LDS granule = half*256 + w*64 + l  (row = g/4, c = g%4),
  // global source granule column = c ^ ((row>>1)&3).
  const u16* gsrc[8];
  u16* ldst[8];
#pragma unroll
  for (int j = 0; j < 8; ++j) {
    const int plane = j >> 1;
    const int half = j & 1;
    const int rr = half * 64 + w * 16 + (l >> 2);
    const int cs = (l & 3) ^ ((rr >> 1) & 3);
    const long rowg = ((plane < 2) ? browl : bcol) + rr;
    gsrc[j] = gp[plane] + rowg * 3072 + cs * 8;
    ldst[j] = lds + plane * 4096 + (half * 256 + w * 64 + l) * 8;
  }

  // Fragment LDS offsets (u16 units), swizzle undone on read.
  const int wm = w >> 1, wn = w & 1;
  const int rl = l & 15;
  const int g = l >> 4;
  int aoff[4], boff[4];
#pragma unroll
  for (int i = 0; i < 4; ++i) {
    const int ra = wm * 64 + i * 16 + rl;
    aoff[i] = ra * 32 + ((g ^ ((ra >> 1) & 3)) * 8);
    const int rb = wn * 64 + i * 16 + rl;
    boff[i] = rb * 32 + ((g ^ ((rb >> 1) & 3)) * 8);
  }

  f32x4 acc[4][4] = {};

  for (int kt = 0; kt < 96; ++kt) {
    if (kt) __syncthreads();  // all waves done reading previous tile
    const int k0 = kt * 32;
#pragma unroll
    for (int j = 0; j < 8; ++j) {
      __builtin_amdgcn_global_load_lds(
          (const GLOBAL_AS u32*)(gsrc[j] + k0),
          (LDS_AS u32*)(ldst[j]), 16, 0, 0);
    }
    __syncthreads();  // vmcnt(0) drained before s_barrier -> tile ready

    bf16x8 ah[4], al[4], bh[4], bl[4];
#pragma unroll
    for (int i = 0; i < 4; ++i) {
      ah[i] = *(const bf16x8*)(lds + aoff[i]);
      al[i] = *(const bf16x8*)(lds + 4096 + aoff[i]);
      bh[i] = *(const bf16x8*)(lds + 8192 + boff[i]);
      bl[i] = *(const bf16x8*)(lds + 12288 + boff[i]);
    }
#pragma unroll
    for (int mi = 0; mi < 4; ++mi) {
#pragma unroll
      for (int ni = 0; ni < 4; ++ni) {
        acc[mi][ni] = __builtin_amdgcn_mfma_f32_16x16x32_bf16(ah[mi], bh[ni],
                                                              acc[mi][ni], 0, 0, 0);
        acc[mi][ni] = __builtin_amdgcn_mfma_f32_16x16x32_bf16(ah[mi], bl[ni],
                                                              acc[mi][ni], 0, 0, 0);
        acc[mi][ni] = __builtin_amdgcn_mfma_f32_16x16x32_bf16(al[mi], bh[ni],
                                                              acc[mi][ni], 0, 0, 0);
      }
    }
  }

  // ---- fused epilogue ----
  // acc element (mi,ni,r): row-in-tile = wm*64 + mi*16 + g*4 + r,
  //                        col-in-tile tc = wn*64 + ni*16 + rl.
  // tc -> gate = tc>>5 = 2*wn + (ni>>1), unit = bn*32 + (ni&1)*16 + rl.
  float bv[4];
#pragma unroll
  for (int ni = 0; ni < 4; ++ni) {
    bv[ni] = bias[(2 * wn + (ni >> 1)) * 1024 + bn * 32 + (ni & 1) * 16 + rl];
  }

  float* ldsf = (float*)lds;  // reuse staging LDS: fp32[64][128] = 32 KB
  const int u = t & 31;       // unit-in-block for the ew phase
  const int rsub = t >> 5;    // 0..7
  const long gu = (long)bn * 32 + u;

#pragma unroll
  for (int hp = 0; hp < 2; ++hp) {
    __syncthreads();  // previous LDS use (MFMA reads / prior half) done
    if (wm == hp) {
#pragma unroll
      for (int mi = 0; mi < 4; ++mi) {
#pragma unroll
        for (int ni = 0; ni < 4; ++ni) {
#pragma unroll
          for (int r = 0; r < 4; ++r) {
            ldsf[(mi * 16 + g * 4 + r) * 128 + wn * 64 + ni * 16 + rl] =
                acc[mi][ni][r] + bv[ni];
          }
        }
      }
    }
    __syncthreads();
#pragma unroll
    for (int q = 0; q < 8; ++q) {
      const int rowl = q * 8 + rsub;            // 0..63
      const long row = browg + hp * 64 + rowl;  // global batch row
      const float zf = z[row], zbf = zb[row];
      const bool flush = zf > 0.5f;
      const bool update = (!flush) && (zbf > 0.5f);
      const float si = ldsf[rowl * 128 + u];
      const float sg = ldsf[rowl * 128 + 32 + u];
      const float so = ldsf[rowl * 128 + 64 + u];
      const float sf = ldsf[rowl * 128 + 96 + u];
      const float I = fast_sigmoid(si);
      const float G = fast_tanh(sg);
      const float O = fast_sigmoid(so);
      const float F = fast_sigmoid(sf);
      const float ig = I * G;
      const long hidx = row * 1024 + gu;
      const float cv = c[hidx];
      const float hv = h[hidx];
      const float cn = flush ? ig : (update ? (cv * F + ig) : cv);
      const float hn = (flush || update) ? (fast_tanh(cn) * O) : hv;
      out[hidx] = hn;
      out[8388608 + hidx] = cn;
    }
  }
}

// ---------------------------------------------------------------------------
// gemv: s4 = hb*zb @ W[:,4096] + h_new @ R[:,4096] + ht*z @ U[:,4096] + b[4096]
// using the UPDATED h from d_out. One wave per batch row. Forward value of
// the straight-through z_out is the hard threshold (z_tilde > 0.5).
// ---------------------------------------------------------------------------
__global__ __launch_bounds__(256) void gemv_kernel(
    const float* __restrict__ hb, const float* __restrict__ ht,
    const float* __restrict__ z, const float* __restrict__ zb,
    const float* __restrict__ W, const float* __restrict__ R,
    const float* __restrict__ U, const float* __restrict__ bias,
    const float* __restrict__ hnew, float* __restrict__ zout) {
  const int w = threadIdx.x >> 6;
  const int l = threadIdx.x & 63;
  const int b = blockIdx.x * 4 + w;
  const float zf = z[b], zbf = zb[b];
  const float* hbrow = hb + (long)b * 1024;
  const float* hnrow = hnew + (long)b * 1024;
  const float* htrow = ht + (long)b * 1024;
  float acc = 0.0f;
  for (int k = l; k < 1024; k += 64) {
    const long wi = (long)k * 4097 + 4096;
    acc += hbrow[k] * zbf * W[wi];
    acc += hnrow[k] * R[wi];
    acc += htrow[k] * zf * U[wi];
  }
#pragma unroll
  for (int off = 32; off > 0; off >>= 1) acc += __shfl_down(acc, off);
  if (l == 0) {
    const float s4 = acc + bias[4096];
    const float sz = fast_sigmoid(s4);
    float zt = 0.5f * (sz + 1.0f);
    zt = fminf(fmaxf(zt, 0.0f), 1.0f);
    zout[b] = (zt > 0.5f) ? 1.0f : 0.0f;
  }
}

// ---------------------------------------------------------------------------
extern "C" void kernel_launch(void* const* d_in, const int* in_sizes, int n_in,
                              void* d_out, int out_size, void* d_ws, size_t ws_size,
                              hipStream_t stream) {
  const float* hb = (const float*)d_in[0];
  const float* h = (const float*)d_in[1];
  const float* ht = (const float*)d_in[2];
  const float* c = (const float*)d_in[3];
  const float* z = (const float*)d_in[4];
  const float* zb = (const float*)d_in[5];
  const float* W = (const float*)d_in[6];
  const float* R = (const float*)d_in[7];
  const float* U = (const float*)d_in[8];
  const float* bias = (const float*)d_in[9];
  float* out = (float*)d_out;

  // Workspace carve-up: B hi/lo fixed at the front, A chunk after.
  const size_t b_bytes = 2UL * 4096 * 3072 * 2;  // 50,331,648
  u16* Bthi = (u16*)d_ws;
  u16* Btlo = Bthi + 4096L * 3072;
  u16* Ahi = Btlo + 4096L * 3072;

  // A chunk rows: fit hi+lo (12,288 B/row) in the remaining scratch,
  // multiple of 128. ws_size >= 151 MB -> one chunk of 8192 (full batch).
  long chunk = 8192;
  if (ws_size >= b_bytes + 12288) {
    long fit = (long)((ws_size - b_bytes) / 12288) & ~127L;
    if (fit < 128) fit = 128;     // ws too small: best effort
    if (fit < chunk) chunk = fit;
  } else {
    chunk = 128;                  // ws far too small: best effort
  }
  u16* Alo = Ahi + chunk * 3072;

  prep_b<<<dim3(128, 96), 256, 0, stream>>>(W, R, U, Bthi, Btlo);
  for (long r0 = 0; r0 < 8192; r0 += chunk) {
    const long nrows = (8192 - r0 < chunk) ? (8192 - r0) : chunk;
    prep_a<<<(int)nrows, 256, 0, stream>>>(hb, h, ht, z, zb, Ahi, Alo, (int)r0);
    gemm_fused<<<(int)((nrows / 128) * 32), 256, 0, stream>>>(
        Ahi, Alo, Bthi, Btlo, bias, c, h, z, zb, out, (int)r0);
  }
  gemv_kernel<<<2048, 256, 0, stream>>>(hb, ht, z, zb, W, R, U, bias, out,
                                        out + 2L * 8388608);
}

// Round 6
// 564.007 us; speedup vs baseline: 1.7739x; 1.7739x over previous
//
#include <hip/hip_runtime.h>
#include <stdint.h>

// HMLSTM cell fused pipeline for MI355X (gfx950).
// Sizes fixed by the reference: B=8192, IBS=H=ITS=1024, K=3072, G=4096.
//
// Round 1: fused GEMM epilogue (gate-permuted B cols).
// Round 4: ws_size-adaptive M-chunking. PASSED @ 1000 us, gemm 685 us
//          (= 902 TF on 3x bf16-split products: the m97-structure ceiling).
// Round 5: SINGLE fp16 product replaces the 3-product bf16 split.
//          fp16's 11-bit mantissa gives ~1e-3 max error on s (vs accepted
//          absmax 0.0156). MFMA work /3, staging planes 4->2.
//          B pre-scaled x256 (exact pow2) to avoid fp16 subnormals; epilogue
//          multiplies by 1/256.
//
// Workspace layout (75,497,472 B total):
//   Bt [4096][3072] f16 @ 0          (25,165,824 B)  rows = PERMUTED cols,
//                                     values scaled x256
//   A  [chunk][3072] f16 @ 25165824  (50,331,648 B @ chunk=8192)
//
// B-column permutation: source col n (gate = n>>10, unit = n&1023) is stored
// at row p = (unit>>5)*128 + gate*32 + (unit&31). Block bn then covers
// units bn*32..bn*32+31 x all 4 gates in one 128-wide tile.

typedef float f4 __attribute__((ext_vector_type(4)));
typedef float f32x4 __attribute__((ext_vector_type(4)));
typedef _Float16 f16x8 __attribute__((ext_vector_type(8)));
typedef unsigned int u32;
typedef unsigned short u16;
typedef u16 u16x4 __attribute__((ext_vector_type(4)));

#define GLOBAL_AS __attribute__((address_space(1)))
#define LDS_AS __attribute__((address_space(3)))

__device__ __forceinline__ u16 f16_bits(float x) {
  _Float16 h = (_Float16)x;  // v_cvt_f16_f32, RNE
  return __builtin_bit_cast(u16, h);
}
__device__ __forceinline__ float fast_sigmoid(float x) {
  return 1.0f / (1.0f + __expf(-x));
}
__device__ __forceinline__ float fast_tanh(float x) {
  return 2.0f / (1.0f + __expf(-2.0f * x)) - 1.0f;
}

// ---------------------------------------------------------------------------
// prep_a: A = [hb*zb | h | ht*z] -> fp16, row-major, for batch rows
// [row0, row0+gridDim.x); A indexed by LOCAL row (blockIdx.x).
// ---------------------------------------------------------------------------
__global__ __launch_bounds__(256) void prep_a(
    const float* __restrict__ hb, const float* __restrict__ h,
    const float* __restrict__ ht, const float* __restrict__ z,
    const float* __restrict__ zb, u16* __restrict__ A, int row0) {
  const int bl = blockIdx.x;           // local row in A chunk
  const int bg = row0 + bl;            // global batch row
  const int t = threadIdx.x;
  const float zf = z[bg], zbf = zb[bg];
  const float gates[3] = {zbf, 1.0f, zf};
  const float* srcs[3] = {hb, h, ht};
#pragma unroll
  for (int p = 0; p < 3; ++p) {
    const int col = p * 1024 + t * 4;
    f4 v = *(const f4*)(srcs[p] + (long)bg * 1024 + t * 4);
    const float gt = gates[p];
    u16x4 vh;
#pragma unroll
    for (int q = 0; q < 4; ++q) vh[q] = f16_bits(v[q] * gt);
    *(u16x4*)(A + (long)bl * 3072 + col) = vh;
  }
}

// ---------------------------------------------------------------------------
// prep_b: Bt[p][k] = 256 * cat(W,R,U)[k][n] -> fp16, gate-permuted dest row p.
// 32x32 LDS-tiled transpose; grid=(128 n-tiles, 96 k-tiles), 256 threads.
// Source pitch is 4097 (sz column excluded here, handled by gemv).
// x256 scaling (exact pow2) keeps fp16 values well out of subnormal range.
// ---------------------------------------------------------------------------
__global__ __launch_bounds__(256) void prep_b(
    const float* __restrict__ W, const float* __restrict__ R,
    const float* __restrict__ U, u16* __restrict__ Bt) {
  __shared__ float tile[32][33];
  const int tx = threadIdx.x & 31;
  const int ty = threadIdx.x >> 5;
  const int n0 = blockIdx.x * 32;
  const int k0 = blockIdx.y * 32;
  const int piece = k0 >> 10;       // k-tiles never straddle a 1024 boundary
  const int kp0 = k0 & 1023;
  const float* src = (piece == 0) ? W : ((piece == 1) ? R : U);
#pragma unroll
  for (int i = 0; i < 4; ++i) {
    const int kl = ty + i * 8;
    tile[kl][tx] = src[(long)(kp0 + kl) * 4097 + n0 + tx];
  }
  __syncthreads();
  const int gate = n0 >> 10;
  const int ubase = (((n0 & 1023) >> 5) << 7) + (gate << 5);  // p for nl=0
#pragma unroll
  for (int i = 0; i < 4; ++i) {
    const int nl = ty + i * 8;
    const long p = ubase + nl;      // permuted destination row
    Bt[p * 3072 + k0 + tx] = f16_bits(tile[tx][nl] * 256.0f);
  }
}

// ---------------------------------------------------------------------------
// gemm_fused: S = (A @ Bt^T) * (1/256) + bias, with fused activations + cell
// update epilogue, for batch rows [row0, row0 + (gridDim.x/32)*128).
// 128x128 tile, BK=32, 4 waves (each 64x64 = 4x4 frags of 16x16x32 f16 MFMA).
// 2 LDS planes of [128][32] f16 (16 KB), staged via global_load_lds w=16.
// XOR swizzle on 16B granules: LDS granule c of row r holds global granule
// c ^ ((r>>1)&3); swizzle applied on the GLOBAL source address (LDS dest
// stays linear — global_load_lds requirement), undone on the ds_read side.
// Epilogue reuses the LDS (full 32 KB decl) as fp32[64][128], two row-halves.
// ---------------------------------------------------------------------------
__global__ __launch_bounds__(256, 2) void gemm_fused(
    const u16* __restrict__ A, const u16* __restrict__ Bt,
    const float* __restrict__ bias, const float* __restrict__ c,
    const float* __restrict__ h, const float* __restrict__ z,
    const float* __restrict__ zb, float* __restrict__ out, int row0) {
  __shared__ u16 lds[16384];  // 32 KB: first 16 KB = 2 staging planes
  const int t = threadIdx.x;
  const int w = t >> 6;
  const int l = t & 63;

  // XCD-bijective swizzle; gridDim.x = Mtiles*32 is always % 8 == 0.
  const int bid = blockIdx.x;
  const int cpx = gridDim.x >> 3;
  const int bid2 = (bid & 7) * cpx + (bid >> 3);
  const int bm = bid2 >> 5;   // M tile within chunk
  const int bn = bid2 & 31;   // unit-block: units bn*32..+31
  const long browl = (long)bm * 128;         // LOCAL A row base
  const long browg = row0 + browl;           // GLOBAL batch row base
  const long bcol = (long)bn * 128;          // permuted-B row base

  const u16* gp[2] = {A, Bt};

  // Staging: 4 global_load_lds per thread per K-step. Instr j: plane j>>1,
  // half j&1. Linear LDS granule = half*256 + w*64 + l  (row = g/4, c = g%4),
  // global source granule column = c ^ ((row>>1)&3).
  const u16* gsrc[4];
  u16* ldst[4];
#pragma unroll
  for (int j = 0; j < 4; ++j) {
    const int plane = j >> 1;
    const int half = j & 1;
    const int rr = half * 64 + w * 16 + (l >> 2);
    const int cs = (l & 3) ^ ((rr >> 1) & 3);
    const long rowg = ((plane == 0) ? browl : bcol) + rr;
    gsrc[j] = gp[plane] + rowg * 3072 + cs * 8;
    ldst[j] = lds + plane * 4096 + (half * 256 + w * 64 + l) * 8;
  }

  // Fragment LDS offsets (u16 units), swizzle undone on read.
  const int wm = w >> 1, wn = w & 1;
  const int rl = l & 15;
  const int g = l >> 4;
  int aoff[4], boff[4];
#pragma unroll
  for (int i = 0; i < 4; ++i) {
    const int ra = wm * 64 + i * 16 + rl;
    aoff[i] = ra * 32 + ((g ^ ((ra >> 1) & 3)) * 8);
    const int rb = wn * 64 + i * 16 + rl;
    boff[i] = rb * 32 + ((g ^ ((rb >> 1) & 3)) * 8);
  }

  f32x4 acc[4][4] = {};

  for (int kt = 0; kt < 96; ++kt) {
    if (kt) __syncthreads();  // all waves done reading previous tile
    const int k0 = kt * 32;
#pragma unroll
    for (int j = 0; j < 4; ++j) {
      __builtin_amdgcn_global_load_lds(
          (const GLOBAL_AS u32*)(gsrc[j] + k0),
          (LDS_AS u32*)(ldst[j]), 16, 0, 0);
    }
    __syncthreads();  // vmcnt(0) drained before s_barrier -> tile ready

    f16x8 af[4], bf[4];
#pragma unroll
    for (int i = 0; i < 4; ++i) {
      af[i] = *(const f16x8*)(lds + aoff[i]);
      bf[i] = *(const f16x8*)(lds + 4096 + boff[i]);
    }
#pragma unroll
    for (int mi = 0; mi < 4; ++mi) {
#pragma unroll
      for (int ni = 0; ni < 4; ++ni) {
        acc[mi][ni] = __builtin_amdgcn_mfma_f32_16x16x32_f16(af[mi], bf[ni],
                                                             acc[mi][ni], 0, 0, 0);
      }
    }
  }

  // ---- fused epilogue ----
  // acc element (mi,ni,r): row-in-tile = wm*64 + mi*16 + g*4 + r,
  //                        col-in-tile tc = wn*64 + ni*16 + rl.
  // tc -> gate = tc>>5 = 2*wn + (ni>>1), unit = bn*32 + (ni&1)*16 + rl.
  // acc holds 256*s (B was pre-scaled); undo with 1/256.
  float bv[4];
#pragma unroll
  for (int ni = 0; ni < 4; ++ni) {
    bv[ni] = bias[(2 * wn + (ni >> 1)) * 1024 + bn * 32 + (ni & 1) * 16 + rl];
  }

  float* ldsf = (float*)lds;  // reuse staging LDS: fp32[64][128] = 32 KB
  const int u = t & 31;       // unit-in-block for the ew phase
  const int rsub = t >> 5;    // 0..7
  const long gu = (long)bn * 32 + u;

#pragma unroll
  for (int hp = 0; hp < 2; ++hp) {
    __syncthreads();  // previous LDS use (MFMA reads / prior half) done
    if (wm == hp) {
#pragma unroll
      for (int mi = 0; mi < 4; ++mi) {
#pragma unroll
        for (int ni = 0; ni < 4; ++ni) {
#pragma unroll
          for (int r = 0; r < 4; ++r) {
            ldsf[(mi * 16 + g * 4 + r) * 128 + wn * 64 + ni * 16 + rl] =
                acc[mi][ni][r] * 0.00390625f + bv[ni];
          }
        }
      }
    }
    __syncthreads();
#pragma unroll
    for (int q = 0; q < 8; ++q) {
      const int rowl = q * 8 + rsub;            // 0..63
      const long row = browg + hp * 64 + rowl;  // global batch row
      const float zf = z[row], zbf = zb[row];
      const bool flush = zf > 0.5f;
      const bool update = (!flush) && (zbf > 0.5f);
      const float si = ldsf[rowl * 128 + u];
      const float sg = ldsf[rowl * 128 + 32 + u];
      const float so = ldsf[rowl * 128 + 64 + u];
      const float sf = ldsf[rowl * 128 + 96 + u];
      const float I = fast_sigmoid(si);
      const float G = fast_tanh(sg);
      const float O = fast_sigmoid(so);
      const float F = fast_sigmoid(sf);
      const float ig = I * G;
      const long hidx = row * 1024 + gu;
      const float cv = c[hidx];
      const float hv = h[hidx];
      const float cn = flush ? ig : (update ? (cv * F + ig) : cv);
      const float hn = (flush || update) ? (fast_tanh(cn) * O) : hv;
      out[hidx] = hn;
      out[8388608 + hidx] = cn;
    }
  }
}

// ---------------------------------------------------------------------------
// gemv: s4 = hb*zb @ W[:,4096] + h_new @ R[:,4096] + ht*z @ U[:,4096] + b[4096]
// using the UPDATED h from d_out. One wave per batch row; z/zb gates skip
// whole terms (wave-uniform, z is exactly 0.0/1.0). Forward value of the
// straight-through z_out is the hard threshold (z_tilde > 0.5).
// ---------------------------------------------------------------------------
__global__ __launch_bounds__(256) void gemv_kernel(
    const float* __restrict__ hb, const float* __restrict__ ht,
    const float* __restrict__ z, const float* __restrict__ zb,
    const float* __restrict__ W, const float* __restrict__ R,
    const float* __restrict__ U, const float* __restrict__ bias,
    const float* __restrict__ hnew, float* __restrict__ zout) {
  const int w = threadIdx.x >> 6;
  const int l = threadIdx.x & 63;
  const int b = blockIdx.x * 4 + w;
  const float zf = z[b], zbf = zb[b];
  const float* hbrow = hb + (long)b * 1024;
  const float* hnrow = hnew + (long)b * 1024;
  const float* htrow = ht + (long)b * 1024;
  float acc = 0.0f;
  for (int k = l; k < 1024; k += 64) acc += hnrow[k] * R[(long)k * 4097 + 4096];
  if (zbf > 0.5f) {
    for (int k = l; k < 1024; k += 64) acc += hbrow[k] * W[(long)k * 4097 + 4096];
  }
  if (zf > 0.5f) {
    for (int k = l; k < 1024; k += 64) acc += htrow[k] * U[(long)k * 4097 + 4096];
  }
#pragma unroll
  for (int off = 32; off > 0; off >>= 1) acc += __shfl_down(acc, off);
  if (l == 0) {
    const float s4 = acc + bias[4096];
    const float sz = fast_sigmoid(s4);
    float zt = 0.5f * (sz + 1.0f);
    zt = fminf(fmaxf(zt, 0.0f), 1.0f);
    zout[b] = (zt > 0.5f) ? 1.0f : 0.0f;
  }
}

// ---------------------------------------------------------------------------
extern "C" void kernel_launch(void* const* d_in, const int* in_sizes, int n_in,
                              void* d_out, int out_size, void* d_ws, size_t ws_size,
                              hipStream_t stream) {
  const float* hb = (const float*)d_in[0];
  const float* h = (const float*)d_in[1];
  const float* ht = (const float*)d_in[2];
  const float* c = (const float*)d_in[3];
  const float* z = (const float*)d_in[4];
  const float* zb = (const float*)d_in[5];
  const float* W = (const float*)d_in[6];
  const float* R = (const float*)d_in[7];
  const float* U = (const float*)d_in[8];
  const float* bias = (const float*)d_in[9];
  float* out = (float*)d_out;

  // Workspace carve-up: Bt fixed at the front, A chunk after.
  const size_t b_bytes = 4096UL * 3072 * 2;  // 25,165,824
  u16* Bt = (u16*)d_ws;
  u16* A = Bt + 4096L * 3072;

  // A chunk rows: fit 6144 B/row in remaining scratch, multiple of 128.
  // ws_size >= 75.5 MB -> one chunk of 8192 (full batch).
  long chunk = 8192;
  if (ws_size >= b_bytes + 6144) {
    long fit = (long)((ws_size - b_bytes) / 6144) & ~127L;
    if (fit < 128) fit = 128;     // ws too small: best effort
    if (fit < chunk) chunk = fit;
  } else {
    chunk = 128;                  // ws far too small: best effort
  }

  prep_b<<<dim3(128, 96), 256, 0, stream>>>(W, R, U, Bt);
  for (long r0 = 0; r0 < 8192; r0 += chunk) {
    const long nrows = (8192 - r0 < chunk) ? (8192 - r0) : chunk;
    prep_a<<<(int)nrows, 256, 0, stream>>>(hb, h, ht, z, zb, A, (int)r0);
    gemm_fused<<<(int)((nrows / 128) * 32), 256, 0, stream>>>(
        A, Bt, bias, c, h, z, zb, out, (int)r0);
  }
  gemv_kernel<<<2048, 256, 0, stream>>>(hb, ht, z, zb, W, R, U, bias, out,
                                        out + 2L * 8388608);
}

// Round 8
// 516.791 us; speedup vs baseline: 1.9360x; 1.0914x over previous
//
#include <hip/hip_runtime.h>
#include <stdint.h>

// HMLSTM cell fused pipeline for MI355X (gfx950).
// Sizes fixed by the reference: B=8192, IBS=H=ITS=1024, K=3072, G=4096.
//
// Round 4: PASSED 1000 us (gemm 685, 3x bf16-split = 902 TF, m97 ceiling).
// Round 5: single fp16 product. PASSED 564 us (gemm 315 us, 654 TF,
//          MfmaUtil 29%): per-K-step fixed costs (2 barriers + vmcnt(0)
//          drain) now dominate 16-MFMA iterations.
// Round 6: BK 32 -> 64. 32 MFMA per barrier-pair, 48 iters instead of 96;
//          halves the per-iteration latency exposures. Swizzle: granule c of
//          row r <-> c ^ (r&7) (8 granules/row); 2-way max per 16-lane
//          phase on ds_read (free, m136).
// Round 7: identical resubmit (round-6 bench never ran: broker timeout).
//
// Workspace layout (75,497,472 B total):
//   Bt [4096][3072] f16 @ 0          (25,165,824 B)  rows = PERMUTED cols,
//                                     values scaled x256
//   A  [chunk][3072] f16 @ 25165824  (50,331,648 B @ chunk=8192)
//
// B-column permutation: source col n (gate = n>>10, unit = n&1023) is stored
// at row p = (unit>>5)*128 + gate*32 + (unit&31). Block bn then covers
// units bn*32..bn*32+31 x all 4 gates in one 128-wide tile.

typedef float f4 __attribute__((ext_vector_type(4)));
typedef float f32x4 __attribute__((ext_vector_type(4)));
typedef _Float16 f16x8 __attribute__((ext_vector_type(8)));
typedef unsigned int u32;
typedef unsigned short u16;
typedef u16 u16x4 __attribute__((ext_vector_type(4)));

#define GLOBAL_AS __attribute__((address_space(1)))
#define LDS_AS __attribute__((address_space(3)))

__device__ __forceinline__ u16 f16_bits(float x) {
  _Float16 h = (_Float16)x;  // v_cvt_f16_f32, RNE
  return __builtin_bit_cast(u16, h);
}
__device__ __forceinline__ float fast_sigmoid(float x) {
  return 1.0f / (1.0f + __expf(-x));
}
__device__ __forceinline__ float fast_tanh(float x) {
  return 2.0f / (1.0f + __expf(-2.0f * x)) - 1.0f;
}

// ---------------------------------------------------------------------------
// prep_a: A = [hb*zb | h | ht*z] -> fp16, row-major, for batch rows
// [row0, row0+gridDim.x); A indexed by LOCAL row (blockIdx.x).
// ---------------------------------------------------------------------------
__global__ __launch_bounds__(256) void prep_a(
    const float* __restrict__ hb, const float* __restrict__ h,
    const float* __restrict__ ht, const float* __restrict__ z,
    const float* __restrict__ zb, u16* __restrict__ A, int row0) {
  const int bl = blockIdx.x;           // local row in A chunk
  const int bg = row0 + bl;            // global batch row
  const int t = threadIdx.x;
  const float zf = z[bg], zbf = zb[bg];
  const float gates[3] = {zbf, 1.0f, zf};
  const float* srcs[3] = {hb, h, ht};
#pragma unroll
  for (int p = 0; p < 3; ++p) {
    const int col = p * 1024 + t * 4;
    f4 v = *(const f4*)(srcs[p] + (long)bg * 1024 + t * 4);
    const float gt = gates[p];
    u16x4 vh;
#pragma unroll
    for (int q = 0; q < 4; ++q) vh[q] = f16_bits(v[q] * gt);
    *(u16x4*)(A + (long)bl * 3072 + col) = vh;
  }
}

// ---------------------------------------------------------------------------
// prep_b: Bt[p][k] = 256 * cat(W,R,U)[k][n] -> fp16, gate-permuted dest row p.
// 32x32 LDS-tiled transpose; grid=(128 n-tiles, 96 k-tiles), 256 threads.
// Source pitch is 4097 (sz column excluded here, handled by gemv).
// x256 scaling (exact pow2) keeps fp16 values well out of subnormal range.
// ---------------------------------------------------------------------------
__global__ __launch_bounds__(256) void prep_b(
    const float* __restrict__ W, const float* __restrict__ R,
    const float* __restrict__ U, u16* __restrict__ Bt) {
  __shared__ float tile[32][33];
  const int tx = threadIdx.x & 31;
  const int ty = threadIdx.x >> 5;
  const int n0 = blockIdx.x * 32;
  const int k0 = blockIdx.y * 32;
  const int piece = k0 >> 10;       // k-tiles never straddle a 1024 boundary
  const int kp0 = k0 & 1023;
  const float* src = (piece == 0) ? W : ((piece == 1) ? R : U);
#pragma unroll
  for (int i = 0; i < 4; ++i) {
    const int kl = ty + i * 8;
    tile[kl][tx] = src[(long)(kp0 + kl) * 4097 + n0 + tx];
  }
  __syncthreads();
  const int gate = n0 >> 10;
  const int ubase = (((n0 & 1023) >> 5) << 7) + (gate << 5);  // p for nl=0
#pragma unroll
  for (int i = 0; i < 4; ++i) {
    const int nl = ty + i * 8;
    const long p = ubase + nl;      // permuted destination row
    Bt[p * 3072 + k0 + tx] = f16_bits(tile[tx][nl] * 256.0f);
  }
}

// ---------------------------------------------------------------------------
// gemm_fused: S = (A @ Bt^T) * (1/256) + bias, with fused activations + cell
// update epilogue, for batch rows [row0, row0 + (gridDim.x/32)*128).
// 128x128 tile, BK=64, 4 waves (each 64x64; per iter 2 kk-substeps x 16
// MFMA 16x16x32 f16 = 32 MFMA per barrier-pair).
// 2 LDS planes of [128 rows][64 k] f16 (16 KB each), staged via
// global_load_lds w=16 (8 instrs/thread/iter). XOR swizzle on 16B granules
// (8 per row): LDS granule c of row r holds global granule c ^ (r&7);
// applied on the GLOBAL source address (LDS dest stays linear), undone on
// the ds_read side -> 2-way max bank aliasing per 16-lane phase (free).
// Epilogue reuses the 32 KB LDS as fp32[64][128], two row-halves.
// ---------------------------------------------------------------------------
__global__ __launch_bounds__(256, 2) void gemm_fused(
    const u16* __restrict__ A, const u16* __restrict__ Bt,
    const float* __restrict__ bias, const float* __restrict__ c,
    const float* __restrict__ h, const float* __restrict__ z,
    const float* __restrict__ zb, float* __restrict__ out, int row0) {
  __shared__ u16 lds[16384];  // 32 KB: plane A @ 0, plane B @ 8192 (u16 idx)
  const int t = threadIdx.x;
  const int w = t >> 6;
  const int l = t & 63;

  // XCD-bijective swizzle; gridDim.x = Mtiles*32 is always % 8 == 0.
  const int bid = blockIdx.x;
  const int cpx = gridDim.x >> 3;
  const int bid2 = (bid & 7) * cpx + (bid >> 3);
  const int bm = bid2 >> 5;   // M tile within chunk
  const int bn = bid2 & 31;   // unit-block: units bn*32..+31
  const long browl = (long)bm * 128;         // LOCAL A row base
  const long browg = row0 + browl;           // GLOBAL batch row base
  const long bcol = (long)bn * 128;          // permuted-B row base

  const u16* gp[2] = {A, Bt};

  // Staging: 8 global_load_lds per thread per iter. Instr j (plane j>>2,
  // quarter j&3): granule gnum = (j&3)*256 + t; row r = gnum>>3 (0..127),
  // col c = gnum&7; global source col = c ^ (r&7); LDS dest linear.
  const u16* gsrc[8];
  u16* ldst[8];
#pragma unroll
  for (int j = 0; j < 8; ++j) {
    const int plane = j >> 2;
    const int gnum = (j & 3) * 256 + t;
    const int rr = gnum >> 3;
    const int cs = (gnum & 7) ^ (rr & 7);
    const long rowg = ((plane == 0) ? browl : bcol) + rr;
    gsrc[j] = gp[plane] + rowg * 3072 + cs * 8;
    ldst[j] = lds + plane * 8192 + gnum * 8;
  }

  // Fragment LDS offsets (u16 units), swizzle undone on read.
  // Row stride 64 f16 = 128 B; granule within row = kk*4 + g, XOR (row&7).
  const int wm = w >> 1, wn = w & 1;
  const int rl = l & 15;
  const int g = l >> 4;
  int aoff[4][2], boff[4][2];
#pragma unroll
  for (int i = 0; i < 4; ++i) {
#pragma unroll
    for (int kk = 0; kk < 2; ++kk) {
      const int ra = wm * 64 + i * 16 + rl;
      aoff[i][kk] = ra * 64 + (((kk * 4 + g) ^ (ra & 7)) * 8);
      const int rb = wn * 64 + i * 16 + rl;
      boff[i][kk] = rb * 64 + (((kk * 4 + g) ^ (rb & 7)) * 8);
    }
  }

  f32x4 acc[4][4] = {};

  for (int kt = 0; kt < 48; ++kt) {
    if (kt) __syncthreads();  // all waves done reading previous tile
    const int k0 = kt * 64;
#pragma unroll
    for (int j = 0; j < 8; ++j) {
      __builtin_amdgcn_global_load_lds(
          (const GLOBAL_AS u32*)(gsrc[j] + k0),
          (LDS_AS u32*)(ldst[j]), 16, 0, 0);
    }
    __syncthreads();  // vmcnt(0) drained before s_barrier -> tile ready

#pragma unroll
    for (int kk = 0; kk < 2; ++kk) {
      f16x8 af[4], bf[4];
#pragma unroll
      for (int i = 0; i < 4; ++i) {
        af[i] = *(const f16x8*)(lds + aoff[i][kk]);
        bf[i] = *(const f16x8*)(lds + 8192 + boff[i][kk]);
      }
#pragma unroll
      for (int mi = 0; mi < 4; ++mi) {
#pragma unroll
        for (int ni = 0; ni < 4; ++ni) {
          acc[mi][ni] = __builtin_amdgcn_mfma_f32_16x16x32_f16(
              af[mi], bf[ni], acc[mi][ni], 0, 0, 0);
        }
      }
    }
  }

  // ---- fused epilogue ----
  // acc element (mi,ni,r): row-in-tile = wm*64 + mi*16 + g*4 + r,
  //                        col-in-tile tc = wn*64 + ni*16 + rl.
  // tc -> gate = tc>>5 = 2*wn + (ni>>1), unit = bn*32 + (ni&1)*16 + rl.
  // acc holds 256*s (B was pre-scaled); undo with 1/256.
  float bv[4];
#pragma unroll
  for (int ni = 0; ni < 4; ++ni) {
    bv[ni] = bias[(2 * wn + (ni >> 1)) * 1024 + bn * 32 + (ni & 1) * 16 + rl];
  }

  float* ldsf = (float*)lds;  // reuse staging LDS: fp32[64][128] = 32 KB
  const int u = t & 31;       // unit-in-block for the ew phase
  const int rsub = t >> 5;    // 0..7
  const long gu = (long)bn * 32 + u;

#pragma unroll
  for (int hp = 0; hp < 2; ++hp) {
    __syncthreads();  // previous LDS use (MFMA reads / prior half) done
    if (wm == hp) {
#pragma unroll
      for (int mi = 0; mi < 4; ++mi) {
#pragma unroll
        for (int ni = 0; ni < 4; ++ni) {
#pragma unroll
          for (int r = 0; r < 4; ++r) {
            ldsf[(mi * 16 + g * 4 + r) * 128 + wn * 64 + ni * 16 + rl] =
                acc[mi][ni][r] * 0.00390625f + bv[ni];
          }
        }
      }
    }
    __syncthreads();
#pragma unroll
    for (int q = 0; q < 8; ++q) {
      const int rowl = q * 8 + rsub;            // 0..63
      const long row = browg + hp * 64 + rowl;  // global batch row
      const float zf = z[row], zbf = zb[row];
      const bool flush = zf > 0.5f;
      const bool update = (!flush) && (zbf > 0.5f);
      const float si = ldsf[rowl * 128 + u];
      const float sg = ldsf[rowl * 128 + 32 + u];
      const float so = ldsf[rowl * 128 + 64 + u];
      const float sf = ldsf[rowl * 128 + 96 + u];
      const float I = fast_sigmoid(si);
      const float G = fast_tanh(sg);
      const float O = fast_sigmoid(so);
      const float F = fast_sigmoid(sf);
      const float ig = I * G;
      const long hidx = row * 1024 + gu;
      const float cv = c[hidx];
      const float hv = h[hidx];
      const float cn = flush ? ig : (update ? (cv * F + ig) : cv);
      const float hn = (flush || update) ? (fast_tanh(cn) * O) : hv;
      out[hidx] = hn;
      out[8388608 + hidx] = cn;
    }
  }
}

// ---------------------------------------------------------------------------
// gemv: s4 = hb*zb @ W[:,4096] + h_new @ R[:,4096] + ht*z @ U[:,4096] + b[4096]
// using the UPDATED h from d_out. One wave per batch row; z/zb gates skip
// whole terms (wave-uniform, z is exactly 0.0/1.0). Forward value of the
// straight-through z_out is the hard threshold (z_tilde > 0.5).
// ---------------------------------------------------------------------------
__global__ __launch_bounds__(256) void gemv_kernel(
    const float* __restrict__ hb, const float* __restrict__ ht,
    const float* __restrict__ z, const float* __restrict__ zb,
    const float* __restrict__ W, const float* __restrict__ R,
    const float* __restrict__ U, const float* __restrict__ bias,
    const float* __restrict__ hnew, float* __restrict__ zout) {
  const int w = threadIdx.x >> 6;
  const int l = threadIdx.x & 63;
  const int b = blockIdx.x * 4 + w;
  const float zf = z[b], zbf = zb[b];
  const float* hbrow = hb + (long)b * 1024;
  const float* hnrow = hnew + (long)b * 1024;
  const float* htrow = ht + (long)b * 1024;
  float acc = 0.0f;
  for (int k = l; k < 1024; k += 64) acc += hnrow[k] * R[(long)k * 4097 + 4096];
  if (zbf > 0.5f) {
    for (int k = l; k < 1024; k += 64) acc += hbrow[k] * W[(long)k * 4097 + 4096];
  }
  if (zf > 0.5f) {
    for (int k = l; k < 1024; k += 64) acc += htrow[k] * U[(long)k * 4097 + 4096];
  }
#pragma unroll
  for (int off = 32; off > 0; off >>= 1) acc += __shfl_down(acc, off);
  if (l == 0) {
    const float s4 = acc + bias[4096];
    const float sz = fast_sigmoid(s4);
    float zt = 0.5f * (sz + 1.0f);
    zt = fminf(fmaxf(zt, 0.0f), 1.0f);
    zout[b] = (zt > 0.5f) ? 1.0f : 0.0f;
  }
}

// ---------------------------------------------------------------------------
extern "C" void kernel_launch(void* const* d_in, const int* in_sizes, int n_in,
                              void* d_out, int out_size, void* d_ws, size_t ws_size,
                              hipStream_t stream) {
  const float* hb = (const float*)d_in[0];
  const float* h = (const float*)d_in[1];
  const float* ht = (const float*)d_in[2];
  const float* c = (const float*)d_in[3];
  const float* z = (const float*)d_in[4];
  const float* zb = (const float*)d_in[5];
  const float* W = (const float*)d_in[6];
  const float* R = (const float*)d_in[7];
  const float* U = (const float*)d_in[8];
  const float* bias = (const float*)d_in[9];
  float* out = (float*)d_out;

  // Workspace carve-up: Bt fixed at the front, A chunk after.
  const size_t b_bytes = 4096UL * 3072 * 2;  // 25,165,824
  u16* Bt = (u16*)d_ws;
  u16* A = Bt + 4096L * 3072;

  // A chunk rows: fit 6144 B/row in remaining scratch, multiple of 128.
  // ws_size >= 75.5 MB -> one chunk of 8192 (full batch).
  long chunk = 8192;
  if (ws_size >= b_bytes + 6144) {
    long fit = (long)((ws_size - b_bytes) / 6144) & ~127L;
    if (fit < 128) fit = 128;     // ws too small: best effort
    if (fit < chunk) chunk = fit;
  } else {
    chunk = 128;                  // ws far too small: best effort
  }

  prep_b<<<dim3(128, 96), 256, 0, stream>>>(W, R, U, Bt);
  for (long r0 = 0; r0 < 8192; r0 += chunk) {
    const long nrows = (8192 - r0 < chunk) ? (8192 - r0) : chunk;
    prep_a<<<(int)nrows, 256, 0, stream>>>(hb, h, ht, z, zb, A, (int)r0);
    gemm_fused<<<(int)((nrows / 128) * 32), 256, 0, stream>>>(
        A, Bt, bias, c, h, z, zb, out, (int)r0);
  }
  gemv_kernel<<<2048, 256, 0, stream>>>(hb, ht, z, zb, W, R, U, bias, out,
                                        out + 2L * 8388608);
}

// Round 11
// 461.043 us; speedup vs baseline: 2.1701x; 1.1209x over previous
//
#include <hip/hip_runtime.h>
#include <stdint.h>

// HMLSTM cell fused pipeline for MI355X (gfx950).
// Sizes fixed by the reference: B=8192, IBS=H=ITS=1024, K=3072, G=4096.
//
// Round 4: PASSED 1000 us (gemm 685, 3x bf16-split = 902 TF, m97 ceiling).
// Round 5: single fp16 product. PASSED 564 us (gemm 315 us, MfmaUtil 29%).
// Round 6/8: BK 32 -> 64, 32 MFMA per barrier-pair. PASSED 517 us
//          (gemm 250 us = 824 TF, ~91% of m97-structure ceiling).
// Round 8 analysis: ~267 us non-gemm. gemv's W/R/U column reads are
//          stride-16KB -> 25M uncoalesced L2 requests (~150-190 us).
// Round 9: prep_cols gathers the 3 sz-columns into contiguous ws once;
//          gemv reads everything as coalesced float4. gemm untouched.
// Rounds 10-11: identical resubmits (benches never ran: broker timeouts).
//
// Workspace layout (75,509,760 B total):
//   cols [3][1024] f32 @ 0          (12,288 B)  W/R/U column 4096
//   Bt [4096][3072] f16 @ 12288     (25,165,824 B)  rows = PERMUTED cols,
//                                    values scaled x256
//   A  [chunk][3072] f16 @ 25178112 (50,331,648 B @ chunk=8192)
//
// B-column permutation: source col n (gate = n>>10, unit = n&1023) is stored
// at row p = (unit>>5)*128 + gate*32 + (unit&31). Block bn then covers
// units bn*32..bn*32+31 x all 4 gates in one 128-wide tile.

typedef float f4 __attribute__((ext_vector_type(4)));
typedef float f32x4 __attribute__((ext_vector_type(4)));
typedef _Float16 f16x8 __attribute__((ext_vector_type(8)));
typedef unsigned int u32;
typedef unsigned short u16;
typedef u16 u16x4 __attribute__((ext_vector_type(4)));

#define GLOBAL_AS __attribute__((address_space(1)))
#define LDS_AS __attribute__((address_space(3)))

__device__ __forceinline__ u16 f16_bits(float x) {
  _Float16 h = (_Float16)x;  // v_cvt_f16_f32, RNE
  return __builtin_bit_cast(u16, h);
}
__device__ __forceinline__ float fast_sigmoid(float x) {
  return 1.0f / (1.0f + __expf(-x));
}
__device__ __forceinline__ float fast_tanh(float x) {
  return 2.0f / (1.0f + __expf(-2.0f * x)) - 1.0f;
}

// ---------------------------------------------------------------------------
// prep_cols: gather W/R/U[:,4096] (stride 4097) into contiguous cols[3][1024].
// One block; 3072 strided loads total (one-time cost, removes gemv's 25M
// uncoalesced L2 requests).
// ---------------------------------------------------------------------------
__global__ __launch_bounds__(256) void prep_cols(
    const float* __restrict__ W, const float* __restrict__ R,
    const float* __restrict__ U, float* __restrict__ cols) {
  const int t = threadIdx.x;
#pragma unroll
  for (int i = 0; i < 12; ++i) {
    const int e = t + i * 256;         // 0..3071
    const int m = e >> 10;             // 0:W 1:R 2:U
    const int k = e & 1023;
    const float* src = (m == 0) ? W : ((m == 1) ? R : U);
    cols[e] = src[(long)k * 4097 + 4096];
  }
}

// ---------------------------------------------------------------------------
// prep_a: A = [hb*zb | h | ht*z] -> fp16, row-major, for batch rows
// [row0, row0+gridDim.x); A indexed by LOCAL row (blockIdx.x).
// ---------------------------------------------------------------------------
__global__ __launch_bounds__(256) void prep_a(
    const float* __restrict__ hb, const float* __restrict__ h,
    const float* __restrict__ ht, const float* __restrict__ z,
    const float* __restrict__ zb, u16* __restrict__ A, int row0) {
  const int bl = blockIdx.x;           // local row in A chunk
  const int bg = row0 + bl;            // global batch row
  const int t = threadIdx.x;
  const float zf = z[bg], zbf = zb[bg];
  const float gates[3] = {zbf, 1.0f, zf};
  const float* srcs[3] = {hb, h, ht};
#pragma unroll
  for (int p = 0; p < 3; ++p) {
    const int col = p * 1024 + t * 4;
    f4 v = *(const f4*)(srcs[p] + (long)bg * 1024 + t * 4);
    const float gt = gates[p];
    u16x4 vh;
#pragma unroll
    for (int q = 0; q < 4; ++q) vh[q] = f16_bits(v[q] * gt);
    *(u16x4*)(A + (long)bl * 3072 + col) = vh;
  }
}

// ---------------------------------------------------------------------------
// prep_b: Bt[p][k] = 256 * cat(W,R,U)[k][n] -> fp16, gate-permuted dest row p.
// 32x32 LDS-tiled transpose; grid=(128 n-tiles, 96 k-tiles), 256 threads.
// Source pitch is 4097 (sz column handled by prep_cols/gemv).
// x256 scaling (exact pow2) keeps fp16 values well out of subnormal range.
// ---------------------------------------------------------------------------
__global__ __launch_bounds__(256) void prep_b(
    const float* __restrict__ W, const float* __restrict__ R,
    const float* __restrict__ U, u16* __restrict__ Bt) {
  __shared__ float tile[32][33];
  const int tx = threadIdx.x & 31;
  const int ty = threadIdx.x >> 5;
  const int n0 = blockIdx.x * 32;
  const int k0 = blockIdx.y * 32;
  const int piece = k0 >> 10;       // k-tiles never straddle a 1024 boundary
  const int kp0 = k0 & 1023;
  const float* src = (piece == 0) ? W : ((piece == 1) ? R : U);
#pragma unroll
  for (int i = 0; i < 4; ++i) {
    const int kl = ty + i * 8;
    tile[kl][tx] = src[(long)(kp0 + kl) * 4097 + n0 + tx];
  }
  __syncthreads();
  const int gate = n0 >> 10;
  const int ubase = (((n0 & 1023) >> 5) << 7) + (gate << 5);  // p for nl=0
#pragma unroll
  for (int i = 0; i < 4; ++i) {
    const int nl = ty + i * 8;
    const long p = ubase + nl;      // permuted destination row
    Bt[p * 3072 + k0 + tx] = f16_bits(tile[tx][nl] * 256.0f);
  }
}

// ---------------------------------------------------------------------------
// gemm_fused: S = (A @ Bt^T) * (1/256) + bias, with fused activations + cell
// update epilogue, for batch rows [row0, row0 + (gridDim.x/32)*128).
// 128x128 tile, BK=64, 4 waves (each 64x64; per iter 2 kk-substeps x 16
// MFMA 16x16x32 f16 = 32 MFMA per barrier-pair).
// 2 LDS planes of [128 rows][64 k] f16 (16 KB each), staged via
// global_load_lds w=16 (8 instrs/thread/iter). XOR swizzle on 16B granules
// (8 per row): LDS granule c of row r holds global granule c ^ (r&7);
// applied on the GLOBAL source address (LDS dest stays linear), undone on
// the ds_read side -> 2-way max bank aliasing per 16-lane phase (free).
// Epilogue reuses the 32 KB LDS as fp32[64][128], two row-halves.
// ---------------------------------------------------------------------------
__global__ __launch_bounds__(256, 2) void gemm_fused(
    const u16* __restrict__ A, const u16* __restrict__ Bt,
    const float* __restrict__ bias, const float* __restrict__ c,
    const float* __restrict__ h, const float* __restrict__ z,
    const float* __restrict__ zb, float* __restrict__ out, int row0) {
  __shared__ u16 lds[16384];  // 32 KB: plane A @ 0, plane B @ 8192 (u16 idx)
  const int t = threadIdx.x;
  const int w = t >> 6;
  const int l = t & 63;

  // XCD-bijective swizzle; gridDim.x = Mtiles*32 is always % 8 == 0.
  const int bid = blockIdx.x;
  const int cpx = gridDim.x >> 3;
  const int bid2 = (bid & 7) * cpx + (bid >> 3);
  const int bm = bid2 >> 5;   // M tile within chunk
  const int bn = bid2 & 31;   // unit-block: units bn*32..+31
  const long browl = (long)bm * 128;         // LOCAL A row base
  const long browg = row0 + browl;           // GLOBAL batch row base
  const long bcol = (long)bn * 128;          // permuted-B row base

  const u16* gp[2] = {A, Bt};

  // Staging: 8 global_load_lds per thread per iter. Instr j (plane j>>2,
  // quarter j&3): granule gnum = (j&3)*256 + t; row r = gnum>>3 (0..127),
  // col c = gnum&7; global source col = c ^ (r&7); LDS dest linear.
  const u16* gsrc[8];
  u16* ldst[8];
#pragma unroll
  for (int j = 0; j < 8; ++j) {
    const int plane = j >> 2;
    const int gnum = (j & 3) * 256 + t;
    const int rr = gnum >> 3;
    const int cs = (gnum & 7) ^ (rr & 7);
    const long rowg = ((plane == 0) ? browl : bcol) + rr;
    gsrc[j] = gp[plane] + rowg * 3072 + cs * 8;
    ldst[j] = lds + plane * 8192 + gnum * 8;
  }

  // Fragment LDS offsets (u16 units), swizzle undone on read.
  // Row stride 64 f16 = 128 B; granule within row = kk*4 + g, XOR (row&7).
  const int wm = w >> 1, wn = w & 1;
  const int rl = l & 15;
  const int g = l >> 4;
  int aoff[4][2], boff[4][2];
#pragma unroll
  for (int i = 0; i < 4; ++i) {
#pragma unroll
    for (int kk = 0; kk < 2; ++kk) {
      const int ra = wm * 64 + i * 16 + rl;
      aoff[i][kk] = ra * 64 + (((kk * 4 + g) ^ (ra & 7)) * 8);
      const int rb = wn * 64 + i * 16 + rl;
      boff[i][kk] = rb * 64 + (((kk * 4 + g) ^ (rb & 7)) * 8);
    }
  }

  f32x4 acc[4][4] = {};

  for (int kt = 0; kt < 48; ++kt) {
    if (kt) __syncthreads();  // all waves done reading previous tile
    const int k0 = kt * 64;
#pragma unroll
    for (int j = 0; j < 8; ++j) {
      __builtin_amdgcn_global_load_lds(
          (const GLOBAL_AS u32*)(gsrc[j] + k0),
          (LDS_AS u32*)(ldst[j]), 16, 0, 0);
    }
    __syncthreads();  // vmcnt(0) drained before s_barrier -> tile ready

#pragma unroll
    for (int kk = 0; kk < 2; ++kk) {
      f16x8 af[4], bf[4];
#pragma unroll
      for (int i = 0; i < 4; ++i) {
        af[i] = *(const f16x8*)(lds + aoff[i][kk]);
        bf[i] = *(const f16x8*)(lds + 8192 + boff[i][kk]);
      }
#pragma unroll
      for (int mi = 0; mi < 4; ++mi) {
#pragma unroll
        for (int ni = 0; ni < 4; ++ni) {
          acc[mi][ni] = __builtin_amdgcn_mfma_f32_16x16x32_f16(
              af[mi], bf[ni], acc[mi][ni], 0, 0, 0);
        }
      }
    }
  }

  // ---- fused epilogue ----
  // acc element (mi,ni,r): row-in-tile = wm*64 + mi*16 + g*4 + r,
  //                        col-in-tile tc = wn*64 + ni*16 + rl.
  // tc -> gate = tc>>5 = 2*wn + (ni>>1), unit = bn*32 + (ni&1)*16 + rl.
  // acc holds 256*s (B was pre-scaled); undo with 1/256.
  float bv[4];
#pragma unroll
  for (int ni = 0; ni < 4; ++ni) {
    bv[ni] = bias[(2 * wn + (ni >> 1)) * 1024 + bn * 32 + (ni & 1) * 16 + rl];
  }

  float* ldsf = (float*)lds;  // reuse staging LDS: fp32[64][128] = 32 KB
  const int u = t & 31;       // unit-in-block for the ew phase
  const int rsub = t >> 5;    // 0..7
  const long gu = (long)bn * 32 + u;

#pragma unroll
  for (int hp = 0; hp < 2; ++hp) {
    __syncthreads();  // previous LDS use (MFMA reads / prior half) done
    if (wm == hp) {
#pragma unroll
      for (int mi = 0; mi < 4; ++mi) {
#pragma unroll
        for (int ni = 0; ni < 4; ++ni) {
#pragma unroll
          for (int r = 0; r < 4; ++r) {
            ldsf[(mi * 16 + g * 4 + r) * 128 + wn * 64 + ni * 16 + rl] =
                acc[mi][ni][r] * 0.00390625f + bv[ni];
          }
        }
      }
    }
    __syncthreads();
#pragma unroll
    for (int q = 0; q < 8; ++q) {
      const int rowl = q * 8 + rsub;            // 0..63
      const long row = browg + hp * 64 + rowl;  // global batch row
      const float zf = z[row], zbf = zb[row];
      const bool flush = zf > 0.5f;
      const bool update = (!flush) && (zbf > 0.5f);
      const float si = ldsf[rowl * 128 + u];
      const float sg = ldsf[rowl * 128 + 32 + u];
      const float so = ldsf[rowl * 128 + 64 + u];
      const float sf = ldsf[rowl * 128 + 96 + u];
      const float I = fast_sigmoid(si);
      const float G = fast_tanh(sg);
      const float O = fast_sigmoid(so);
      const float F = fast_sigmoid(sf);
      const float ig = I * G;
      const long hidx = row * 1024 + gu;
      const float cv = c[hidx];
      const float hv = h[hidx];
      const float cn = flush ? ig : (update ? (cv * F + ig) : cv);
      const float hn = (flush || update) ? (fast_tanh(cn) * O) : hv;
      out[hidx] = hn;
      out[8388608 + hidx] = cn;
    }
  }
}

// ---------------------------------------------------------------------------
// gemv: s4 = hb*zb @ wcol + h_new @ rcol + ht*z @ ucol + b[4096], with the
// UPDATED h from d_out and the pre-gathered contiguous columns. Fully
// coalesced float4 loads. One wave per batch row; z/zb gates skip whole
// terms (wave-uniform). Forward z_out = hard threshold (z_tilde > 0.5).
// ---------------------------------------------------------------------------
__global__ __launch_bounds__(256) void gemv_kernel(
    const float* __restrict__ hb, const float* __restrict__ ht,
    const float* __restrict__ z, const float* __restrict__ zb,
    const float* __restrict__ cols, const float* __restrict__ bias,
    const float* __restrict__ hnew, float* __restrict__ zout) {
  const int w = threadIdx.x >> 6;
  const int l = threadIdx.x & 63;
  const int b = blockIdx.x * 4 + w;
  const float zf = z[b], zbf = zb[b];
  const float* wcol = cols;
  const float* rcol = cols + 1024;
  const float* ucol = cols + 2048;
  const float* hbrow = hb + (long)b * 1024;
  const float* hnrow = hnew + (long)b * 1024;
  const float* htrow = ht + (long)b * 1024;
  float acc = 0.0f;
#pragma unroll
  for (int i = 0; i < 4; ++i) {
    const int k4 = (l + i * 64) * 4;
    const f4 hv = *(const f4*)(hnrow + k4);
    const f4 rv = *(const f4*)(rcol + k4);
    acc += hv.x * rv.x + hv.y * rv.y + hv.z * rv.z + hv.w * rv.w;
  }
  if (zbf > 0.5f) {
#pragma unroll
    for (int i = 0; i < 4; ++i) {
      const int k4 = (l + i * 64) * 4;
      const f4 hv = *(const f4*)(hbrow + k4);
      const f4 wv = *(const f4*)(wcol + k4);
      acc += hv.x * wv.x + hv.y * wv.y + hv.z * wv.z + hv.w * wv.w;
    }
  }
  if (zf > 0.5f) {
#pragma unroll
    for (int i = 0; i < 4; ++i) {
      const int k4 = (l + i * 64) * 4;
      const f4 hv = *(const f4*)(htrow + k4);
      const f4 uv = *(const f4*)(ucol + k4);
      acc += hv.x * uv.x + hv.y * uv.y + hv.z * uv.z + hv.w * uv.w;
    }
  }
#pragma unroll
  for (int off = 32; off > 0; off >>= 1) acc += __shfl_down(acc, off);
  if (l == 0) {
    const float s4 = acc + bias[4096];
    const float sz = fast_sigmoid(s4);
    float zt = 0.5f * (sz + 1.0f);
    zt = fminf(fmaxf(zt, 0.0f), 1.0f);
    zout[b] = (zt > 0.5f) ? 1.0f : 0.0f;
  }
}

// ---------------------------------------------------------------------------
extern "C" void kernel_launch(void* const* d_in, const int* in_sizes, int n_in,
                              void* d_out, int out_size, void* d_ws, size_t ws_size,
                              hipStream_t stream) {
  const float* hb = (const float*)d_in[0];
  const float* h = (const float*)d_in[1];
  const float* ht = (const float*)d_in[2];
  const float* c = (const float*)d_in[3];
  const float* z = (const float*)d_in[4];
  const float* zb = (const float*)d_in[5];
  const float* W = (const float*)d_in[6];
  const float* R = (const float*)d_in[7];
  const float* U = (const float*)d_in[8];
  const float* bias = (const float*)d_in[9];
  float* out = (float*)d_out;

  // Workspace carve-up: cols (12 KB), Bt, A chunk.
  float* cols = (float*)d_ws;
  u16* Bt = (u16*)((char*)d_ws + 12288);
  u16* A = Bt + 4096L * 3072;
  const size_t fixed_bytes = 12288 + 4096UL * 3072 * 2;  // 25,178,112

  // A chunk rows: fit 6144 B/row in remaining scratch, multiple of 128.
  // ws_size >= 75.6 MB -> one chunk of 8192 (full batch).
  long chunk = 8192;
  if (ws_size >= fixed_bytes + 6144) {
    long fit = (long)((ws_size - fixed_bytes) / 6144) & ~127L;
    if (fit < 128) fit = 128;     // ws too small: best effort
    if (fit < chunk) chunk = fit;
  } else {
    chunk = 128;                  // ws far too small: best effort
  }

  prep_cols<<<1, 256, 0, stream>>>(W, R, U, cols);
  prep_b<<<dim3(128, 96), 256, 0, stream>>>(W, R, U, Bt);
  for (long r0 = 0; r0 < 8192; r0 += chunk) {
    const long nrows = (8192 - r0 < chunk) ? (8192 - r0) : chunk;
    prep_a<<<(int)nrows, 256, 0, stream>>>(hb, h, ht, z, zb, A, (int)r0);
    gemm_fused<<<(int)((nrows / 128) * 32), 256, 0, stream>>>(
        A, Bt, bias, c, h, z, zb, out, (int)r0);
  }
  gemv_kernel<<<2048, 256, 0, stream>>>(hb, ht, z, zb, cols, bias, out,
                                        out + 2L * 8388608);
}